// Round 13
// baseline (26.032 us; speedup 1.0000x reference)
//
#include <hip/hip_runtime.h>
#include <math.h>

constexpr int Bn = 64, Sn = 6, Tn = 2000, Cn = 25;
constexpr int COLS = Sn * Tn;              // 12000
constexpr int ROWS = Bn * Sn * Tn;         // 768000
constexpr int BDIM = 256;
constexpr int WV   = 4;                    // waves per block

// ---- fret: each wave pipelines NT=5 tiles of 64 rows, double-buffered ----
constexpr int TROWS = 64;                  // rows per tile (1 per lane)
constexpr int TF4   = TROWS * Cn / 4;      // 400 float4 per tile
constexpr int NT    = 5;                   // tiles per wave (grid = 788 ~ capacity+20)
constexpr int RPW   = NT * TROWS;          // 320 rows per wave
constexpr int RPB   = WV * RPW;            // 1280 rows per block
constexpr int FBLK  = ROWS / RPB;          // 600 fret blocks (exact)
constexpr int FPAD  = 768;

// ---- onset: 64 cols per block, wave w covers batch [16w,16w+16) ----
constexpr int OCOLS = 64;
constexpr int OBLK  = (COLS + OCOLS - 1) / OCOLS;   // 188 onset blocks
constexpr int OPAD  = 192;
constexpr int GRID  = FBLK + OBLK;         // 788; fret FIRST (LPT: short onset = tail)

typedef const __attribute__((address_space(1))) unsigned int guint;
typedef __attribute__((address_space(3)))       unsigned int luint;

// Segmented (<=2 contiguous strings per wave) butterfly reduce + LDS add.
static __device__ __forceinline__ void seg_reduce_add(float* ls, int s, float v, int lane) {
    const int s0 = __shfl(s, 0, 64);
    const int s1 = __shfl(s, 63, 64);
    if (s0 == s1) {                         // wave-uniform branch
        float a = v;
        #pragma unroll
        for (int off = 32; off; off >>= 1) a += __shfl_xor(a, off, 64);
        if (lane == 0) atomicAdd(&ls[s0], a);
    } else {
        float a = (s == s0) ? v : 0.0f;
        float b = (s == s0) ? 0.0f : v;
        #pragma unroll
        for (int off = 32; off; off >>= 1) {
            a += __shfl_xor(a, off, 64);
            b += __shfl_xor(b, off, 64);
        }
        if (lane == 0) { atomicAdd(&ls[s0], a); atomicAdd(&ls[s1], b); }
    }
}

__global__ __launch_bounds__(BDIM) void main_kernel(const float4* __restrict__ x4,
                                                    const int*    __restrict__ tgt,
                                                    const float*  __restrict__ ox,
                                                    const float*  __restrict__ ot,
                                                    float* __restrict__ pf,
                                                    float* __restrict__ po) {
    __shared__ float4 buf4[WV][2][TF4];    // 51.2 KB: wave-private double buffers
    __shared__ float  ws[WV][Sn];          // per-wave string partials
    const int tid  = threadIdx.x;
    const int lane = tid & 63;
    const int w    = tid >> 6;
    if (lane < Sn) ws[w][lane] = 0.0f;     // same-wave LDS ordering: no barrier

    if (blockIdx.x >= FBLK) {
        // ============ onset path: softmax over B, batch-split across waves ============
        const int cb  = blockIdx.x - FBLK;            // onset blocks dispatched LAST
        const int col = cb * OCOLS + lane;            // wave-local column
        float4* ob4 = &buf4[0][0][0];                 // reuse fret buffer: [4][64] float4
        float M = -INFINITY, S = 0.0f, ts = 0.0f, txs = 0.0f;
        if (col < COLS) {
            const int b0 = w * 16;
            #pragma unroll
            for (int h = 0; h < 2; ++h) {             // two 8-batch chunks (reg pressure)
                float xv[8], tv[8];
                #pragma unroll
                for (int k = 0; k < 8; ++k) xv[k] = ox[(b0 + h * 8 + k) * COLS + col];
                #pragma unroll
                for (int k = 0; k < 8; ++k) tv[k] = ot[(b0 + h * 8 + k) * COLS + col];
                float cm = -INFINITY;
                #pragma unroll
                for (int k = 0; k < 8; ++k) cm = fmaxf(cm, xv[k]);
                float cs = 0.0f;
                #pragma unroll
                for (int k = 0; k < 8; ++k) cs += __expf(xv[k] - cm);
                const float nm = fmaxf(M, cm);
                S = S * __expf(M - nm) + cs * __expf(cm - nm);   // exp(-inf)=0 first iter
                M = nm;
                #pragma unroll
                for (int k = 0; k < 8; ++k) { ts += tv[k]; txs += tv[k] * xv[k]; }
            }
        }
        ob4[w * OCOLS + lane] = make_float4(M, S, ts, txs);   // per-wave partial
        __syncthreads();
        if (tid < OCOLS) {                            // wave 0 merges the 4 partials
            float on = 0.0f;
            int   s  = Sn - 1;
            const int c = cb * OCOLS + tid;
            if (c < COLS) {
                s = c / Tn;
                float4 p0 = ob4[0 * OCOLS + tid];
                float Mm = p0.x, Sm = p0.y, tsm = p0.z, txm = p0.w;
                #pragma unroll
                for (int q = 1; q < WV; ++q) {
                    const float4 p = ob4[q * OCOLS + tid];
                    const float nm = fmaxf(Mm, p.x);
                    Sm  = Sm * __expf(Mm - nm) + p.y * __expf(p.x - nm);
                    Mm  = nm;
                    tsm += p.z; txm += p.w;
                }
                on = tsm * (Mm + __logf(Sm)) - txm;
            }
            seg_reduce_add(ws[0], s, on, tid);        // wave 0 only, same-wave DS order
            if (tid < Sn) po[tid * OPAD + cb] = ws[0][tid];
        }
    } else {
        // ===== fret path: wave-autonomous double-buffered async pipeline =====
        const int fb    = blockIdx.x;                 // fret blocks dispatched FIRST
        const int wrow0 = fb * RPB + w * RPW;         // wave's first row (mult of 4)
        const float4* gw = x4 + (long)(wrow0 / 4) * Cn;   // = wrow0*25/4
        float4* bb = &buf4[w][0][0];                  // [2][TF4] wave-private

        // All 5 targets upfront: 5 coalesced 256B dword loads (5 VGPR, static).
        int tcs[NT];
        #pragma unroll
        for (int t = 0; t < NT; ++t) tcs[t] = tgt[wrow0 + t * TROWS + lane];

        // stage(t): 7 x global_load_lds (6 full + 1 exec-masked), 1KB each.
        // LDS dest = wave-uniform base (+lane*16 by HW); global src per-lane.
        auto stage = [&](int t) {
            const int p = t & 1;
            const float4* gs = gw + (long)t * TF4 + lane;
            #pragma unroll
            for (int k = 0; k < 6; ++k)
                __builtin_amdgcn_global_load_lds((guint*)(gs + k * 64),
                                                 (luint*)(bb + p * TF4 + k * 64), 16, 0, 0);
            if (lane < 16)
                __builtin_amdgcn_global_load_lds((guint*)(gs + 384),
                                                 (luint*)(bb + p * TF4 + 384), 16, 0, 0);
        };

        auto compute = [&](int t) {
            const int tc = tcs[t];
            const float* rp = (const float*)(bb + (t & 1) * TF4) + lane * Cn;  // stride 25
            const float xt = rp[tc];                  // 1 ds_read replaces 50 VALU ops
            float m = -INFINITY;
            #pragma unroll
            for (int c = 0; c < Cn; ++c) m = fmaxf(m, rp[c]);
            float ss = 0.0f;
            #pragma unroll
            for (int c = 0; c < Cn; ++c) ss += __expf(rp[c] - m);
            const float nll = m + __logf(ss) - xt;
            const int s = ((wrow0 + t * TROWS + lane) / Tn) % Sn;  // tile: <=2 strings
            seg_reduce_add(ws[w], s, nll, lane);
        };

        stage(0);
        stage(1);                                     // 14 tile-loads + 5 tgt in flight
        #pragma unroll
        for (int t = 0; t < NT; ++t) {
            if (t < NT - 1)
                asm volatile("s_waitcnt vmcnt(7)" ::: "memory");   // tile t done; next flying
            else
                asm volatile("s_waitcnt vmcnt(0)" ::: "memory");   // final tile drain
            compute(t);
            if (t + 2 < NT) {
                asm volatile("s_waitcnt lgkmcnt(0)" ::: "memory"); // buf[t&1] reads retired
                stage(t + 2);                                      // overwrite buffer t&1
            }
        }
        __syncthreads();                              // once per block: combine 4 waves
        if (tid < Sn)
            pf[tid * FPAD + fb] = ws[0][tid] + ws[1][tid] + ws[2][tid] + ws[3][tid];
    }
}

__global__ __launch_bounds__(1024) void finish_kernel(const float* __restrict__ pf,
                                                      const float* __restrict__ po,
                                                      float* __restrict__ out) {
    __shared__ float acc[2 * Sn];
    const int tid  = threadIdx.x;
    const int lane = tid & 63;
    if (tid < 2 * Sn) acc[tid] = 0.0f;
    __syncthreads();

    // ---- fret partials: 6 coalesced sweeps over 600 entries ----
    float fs[Sn];
    #pragma unroll
    for (int s = 0; s < Sn; ++s) {
        float v = 0.0f;
        for (int i = tid; i < FBLK; i += 1024) v += pf[s * FPAD + i];
        fs[s] = v;
    }
    #pragma unroll
    for (int off = 32; off; off >>= 1) {
        #pragma unroll
        for (int s = 0; s < Sn; ++s) fs[s] += __shfl_xor(fs[s], off, 64);
    }
    if (lane == 0) {
        #pragma unroll
        for (int s = 0; s < Sn; ++s) atomicAdd(&acc[s], fs[s]);
    }

    // ---- onset partials: wave w sums string w (188 entries) ----
    const int wv = tid >> 6;
    if (wv < Sn) {
        float v = 0.0f;
        for (int i = lane; i < OBLK; i += 64) v += po[wv * OPAD + i];
        #pragma unroll
        for (int off = 32; off; off >>= 1) v += __shfl_xor(v, off, 64);
        if (lane == 0) acc[Sn + wv] = v;
    }
    __syncthreads();

    if (tid == 0) {
        float fret = 0.0f, on = 0.0f, fsv[Sn], osv[Sn];
        #pragma unroll
        for (int s = 0; s < Sn; ++s) {
            fsv[s] = acc[s] * (1.0f / Bn);            // mean over batch
            osv[s] = acc[Sn + s];
            fret += fsv[s];
            on   += osv[s];
        }
        out[0] = 0.5f * fret + 0.5f * on;             // WEIGHT_FRET_ONSET = 0.5
        out[1] = fret;
        out[2] = on;
        #pragma unroll
        for (int s = 0; s < Sn; ++s) { out[3 + s] = fsv[s]; out[9 + s] = osv[s]; }
    }
}

extern "C" void kernel_launch(void* const* d_in, const int* in_sizes, int n_in,
                              void* d_out, int out_size, void* d_ws, size_t ws_size,
                              hipStream_t stream) {
    const float* output_fret  = (const float*)d_in[0];
    const int*   target_fret  = (const int*)d_in[1];
    const float* output_onset = (const float*)d_in[2];
    const float* target_onset = (const float*)d_in[3];
    float* pf  = (float*)d_ws;                 // [Sn][FPAD]
    float* po  = pf + Sn * FPAD;               // [Sn][OPAD]
    float* out = (float*)d_out;

    main_kernel<<<GRID, BDIM, 0, stream>>>((const float4*)output_fret, target_fret,
                                           output_onset, target_onset, pf, po);
    finish_kernel<<<1, 1024, 0, stream>>>(pf, po, out);
}

// Round 14
// 24.963 us; speedup vs baseline: 1.0428x; 1.0428x over previous
//
#include <hip/hip_runtime.h>
#include <math.h>

constexpr int Bn = 64, Sn = 6, Tn = 2000, Cn = 25;
constexpr int COLS = Sn * Tn;              // 12000
constexpr int ROWS = Bn * Sn * Tn;         // 768000
constexpr int BDIM = 256;
constexpr int WV   = 4;                    // waves per block

// ---- fret: each wave pipelines NT=4 tiles of 64 rows, double-buffered (R12) ----
constexpr int TROWS = 64;                  // rows per tile (1 per lane)
constexpr int TF4   = TROWS * Cn / 4;      // 400 float4 per tile
constexpr int NT    = 4;                   // tiles per wave
constexpr int RPW   = NT * TROWS;          // 256 rows per wave
constexpr int RPB   = WV * RPW;            // 1024 rows per block
constexpr int FBLK  = ROWS / RPB;          // 750 fret blocks (exact)
constexpr int FPAD  = 768;

// ---- onset: 64 cols per block, wave w covers batch [16w,16w+16) ----
constexpr int OCOLS = 64;
constexpr int OBLK  = (COLS + OCOLS - 1) / OCOLS;   // 188 onset blocks
constexpr int OPAD  = 192;
constexpr int GRID  = FBLK + OBLK;         // 938; fret FIRST (LPT: short onset = tail)

typedef const __attribute__((address_space(1))) unsigned int guint;
typedef __attribute__((address_space(3)))       unsigned int luint;

// Segmented (<=2 contiguous strings per wave) butterfly reduce + LDS add.
static __device__ __forceinline__ void seg_reduce_add(float* ls, int s, float v, int lane) {
    const int s0 = __shfl(s, 0, 64);
    const int s1 = __shfl(s, 63, 64);
    if (s0 == s1) {                         // wave-uniform branch
        float a = v;
        #pragma unroll
        for (int off = 32; off; off >>= 1) a += __shfl_xor(a, off, 64);
        if (lane == 0) atomicAdd(&ls[s0], a);
    } else {
        float a = (s == s0) ? v : 0.0f;
        float b = (s == s0) ? 0.0f : v;
        #pragma unroll
        for (int off = 32; off; off >>= 1) {
            a += __shfl_xor(a, off, 64);
            b += __shfl_xor(b, off, 64);
        }
        if (lane == 0) { atomicAdd(&ls[s0], a); atomicAdd(&ls[s1], b); }
    }
}

__global__ __launch_bounds__(BDIM) void main_kernel(const float4* __restrict__ x4,
                                                    const int*    __restrict__ tgt,
                                                    const float*  __restrict__ ox,
                                                    const float*  __restrict__ ot,
                                                    float* __restrict__ pf,
                                                    float* __restrict__ po) {
    __shared__ float4 buf4[WV][2][TF4];    // 51.2 KB: wave-private double buffers
    __shared__ float  ws[WV][Sn];          // per-wave string partials
    const int tid  = threadIdx.x;
    const int lane = tid & 63;
    const int w    = tid >> 6;
    if (lane < Sn) ws[w][lane] = 0.0f;     // same-wave LDS ordering: no barrier

    if (blockIdx.x >= FBLK) {
        // ============ onset path: softmax over B, batch-split across waves ============
        const int cb  = blockIdx.x - FBLK;            // onset blocks dispatched LAST
        const int col = cb * OCOLS + lane;            // wave-local column
        float4* ob4 = &buf4[0][0][0];                 // reuse fret buffer: [4][64] float4
        float M = -INFINITY, S = 0.0f, ts = 0.0f, txs = 0.0f;
        if (col < COLS) {
            const int b0 = w * 16;
            #pragma unroll
            for (int h = 0; h < 2; ++h) {             // two 8-batch chunks (reg pressure)
                float xv[8], tv[8];
                #pragma unroll
                for (int k = 0; k < 8; ++k) xv[k] = ox[(b0 + h * 8 + k) * COLS + col];
                #pragma unroll
                for (int k = 0; k < 8; ++k) tv[k] = ot[(b0 + h * 8 + k) * COLS + col];
                float cm = -INFINITY;
                #pragma unroll
                for (int k = 0; k < 8; ++k) cm = fmaxf(cm, xv[k]);
                float cs = 0.0f;
                #pragma unroll
                for (int k = 0; k < 8; ++k) cs += __expf(xv[k] - cm);
                const float nm = fmaxf(M, cm);
                S = S * __expf(M - nm) + cs * __expf(cm - nm);   // exp(-inf)=0 first iter
                M = nm;
                #pragma unroll
                for (int k = 0; k < 8; ++k) { ts += tv[k]; txs += tv[k] * xv[k]; }
            }
        }
        ob4[w * OCOLS + lane] = make_float4(M, S, ts, txs);   // per-wave partial
        __syncthreads();
        if (tid < OCOLS) {                            // wave 0 merges the 4 partials
            float on = 0.0f;
            int   s  = Sn - 1;
            const int c = cb * OCOLS + tid;
            if (c < COLS) {
                s = c / Tn;
                float4 p0 = ob4[0 * OCOLS + tid];
                float Mm = p0.x, Sm = p0.y, tsm = p0.z, txm = p0.w;
                #pragma unroll
                for (int q = 1; q < WV; ++q) {
                    const float4 p = ob4[q * OCOLS + tid];
                    const float nm = fmaxf(Mm, p.x);
                    Sm  = Sm * __expf(Mm - nm) + p.y * __expf(p.x - nm);
                    Mm  = nm;
                    tsm += p.z; txm += p.w;
                }
                on = tsm * (Mm + __logf(Sm)) - txm;
            }
            seg_reduce_add(ws[0], s, on, tid);        // wave 0 only, same-wave DS order
            if (tid < Sn) po[tid * OPAD + cb] = ws[0][tid];
        }
    } else {
        // ===== fret path: wave-autonomous double-buffered async pipeline =====
        const int fb    = blockIdx.x;                 // fret blocks dispatched FIRST
        const int wrow0 = fb * RPB + w * RPW;         // wave's first row (mult of 4)
        const float4* gw = x4 + (long)(wrow0 / 4) * Cn;   // = wrow0*25/4
        float4* bb = &buf4[w][0][0];                  // [2][TF4] wave-private

        // All 4 targets upfront: 4 coalesced 256B dword loads (4 VGPR, static).
        int tcs[NT];
        #pragma unroll
        for (int t = 0; t < NT; ++t) tcs[t] = tgt[wrow0 + t * TROWS + lane];

        // stage(t): 7 x global_load_lds (6 full + 1 exec-masked), 1KB each.
        // LDS dest = wave-uniform base (+lane*16 by HW); global src per-lane.
        auto stage = [&](int t) {
            const int p = t & 1;
            const float4* gs = gw + (long)t * TF4 + lane;
            #pragma unroll
            for (int k = 0; k < 6; ++k)
                __builtin_amdgcn_global_load_lds((guint*)(gs + k * 64),
                                                 (luint*)(bb + p * TF4 + k * 64), 16, 0, 0);
            if (lane < 16)
                __builtin_amdgcn_global_load_lds((guint*)(gs + 384),
                                                 (luint*)(bb + p * TF4 + 384), 16, 0, 0);
        };

        auto compute = [&](int t) {
            const int tc = tcs[t];
            const float* rp = (const float*)(bb + (t & 1) * TF4) + lane * Cn;  // stride 25
            const float xt = rp[tc];                  // 1 ds_read replaces 50 VALU ops
            float m = -INFINITY;
            #pragma unroll
            for (int c = 0; c < Cn; ++c) m = fmaxf(m, rp[c]);
            float ss = 0.0f;
            #pragma unroll
            for (int c = 0; c < Cn; ++c) ss += __expf(rp[c] - m);
            const float nll = m + __logf(ss) - xt;
            const int s = ((wrow0 + t * TROWS + lane) / Tn) % Sn;  // tile: <=2 strings
            seg_reduce_add(ws[w], s, nll, lane);
        };

        stage(0);
        stage(1);                                     // 14 tile-loads + 4 tgt in flight
        #pragma unroll
        for (int t = 0; t < NT; ++t) {
            if (t < NT - 1)
                asm volatile("s_waitcnt vmcnt(7)" ::: "memory");   // tile t done; next flying
            else
                asm volatile("s_waitcnt vmcnt(0)" ::: "memory");   // final tile drain
            compute(t);
            if (t + 2 < NT) {
                asm volatile("s_waitcnt lgkmcnt(0)" ::: "memory"); // buf[t&1] reads retired
                stage(t + 2);                                      // overwrite buffer t&1
            }
        }
        __syncthreads();                              // once per block: combine 4 waves
        if (tid < Sn)
            pf[tid * FPAD + fb] = ws[0][tid] + ws[1][tid] + ws[2][tid] + ws[3][tid];
    }
}

__global__ __launch_bounds__(1024) void finish_kernel(const float* __restrict__ pf,
                                                      const float* __restrict__ po,
                                                      float* __restrict__ out) {
    __shared__ float acc[2 * Sn];
    const int tid  = threadIdx.x;
    const int lane = tid & 63;
    if (tid < 2 * Sn) acc[tid] = 0.0f;
    __syncthreads();

    // ---- fret partials: 6 coalesced sweeps over 750 entries ----
    float fs[Sn];
    #pragma unroll
    for (int s = 0; s < Sn; ++s) {
        float v = 0.0f;
        for (int i = tid; i < FBLK; i += 1024) v += pf[s * FPAD + i];
        fs[s] = v;
    }
    #pragma unroll
    for (int off = 32; off; off >>= 1) {
        #pragma unroll
        for (int s = 0; s < Sn; ++s) fs[s] += __shfl_xor(fs[s], off, 64);
    }
    if (lane == 0) {
        #pragma unroll
        for (int s = 0; s < Sn; ++s) atomicAdd(&acc[s], fs[s]);
    }

    // ---- onset partials: wave w sums string w (188 entries) ----
    const int wv = tid >> 6;
    if (wv < Sn) {
        float v = 0.0f;
        for (int i = lane; i < OBLK; i += 64) v += po[wv * OPAD + i];
        #pragma unroll
        for (int off = 32; off; off >>= 1) v += __shfl_xor(v, off, 64);
        if (lane == 0) acc[Sn + wv] = v;
    }
    __syncthreads();

    if (tid == 0) {
        float fret = 0.0f, on = 0.0f, fsv[Sn], osv[Sn];
        #pragma unroll
        for (int s = 0; s < Sn; ++s) {
            fsv[s] = acc[s] * (1.0f / Bn);            // mean over batch
            osv[s] = acc[Sn + s];
            fret += fsv[s];
            on   += osv[s];
        }
        out[0] = 0.5f * fret + 0.5f * on;             // WEIGHT_FRET_ONSET = 0.5
        out[1] = fret;
        out[2] = on;
        #pragma unroll
        for (int s = 0; s < Sn; ++s) { out[3 + s] = fsv[s]; out[9 + s] = osv[s]; }
    }
}

extern "C" void kernel_launch(void* const* d_in, const int* in_sizes, int n_in,
                              void* d_out, int out_size, void* d_ws, size_t ws_size,
                              hipStream_t stream) {
    const float* output_fret  = (const float*)d_in[0];
    const int*   target_fret  = (const int*)d_in[1];
    const float* output_onset = (const float*)d_in[2];
    const float* target_onset = (const float*)d_in[3];
    float* pf  = (float*)d_ws;                 // [Sn][FPAD]
    float* po  = pf + Sn * FPAD;               // [Sn][OPAD]
    float* out = (float*)d_out;

    main_kernel<<<GRID, BDIM, 0, stream>>>((const float4*)output_fret, target_fret,
                                           output_onset, target_onset, pf, po);
    finish_kernel<<<1, 1024, 0, stream>>>(pf, po, out);
}